// Round 1
// baseline (1120.570 us; speedup 1.0000x reference)
//
#include <hip/hip_runtime.h>
#include <math.h>

#define B_   2
#define DM_  768
#define L_   4096
#define DI_  1536
#define NS_  4
#define R_   48
#define XD_  56   // R + 2*NS

__device__ __forceinline__ float softplus_f(float x) {
    // matches jax.nn.softplus = max(x,0) + log1p(exp(-|x|))
    return fmaxf(x, 0.f) + log1pf(expf(-fabsf(x)));
}
__device__ __forceinline__ float silu_f(float x) {
    return x / (1.f + expf(-x));
}

// ---------------------------------------------------------------------------
// Generic channel-major GEMM: C[b][n][l] = act( sum_k A[b][k][l] * W[n][k] )
// A: (B, K, L) with batch stride aBatch; W: (N, K) row-major; C: (B, N, L)
// ACT: 0 = none, 1 = softplus(acc + bias[n]), 2 = LayerNorm applied to A on load
// 128x128 tile, 8x8 micro-tile, BK=16.
// ---------------------------------------------------------------------------
template<int K, int N, int ACT>
__global__ __launch_bounds__(256) void gemm128(
    const float* __restrict__ A, int aBatch,
    const float* __restrict__ Wm,
    float* __restrict__ C,
    const float* __restrict__ bias,
    const float* __restrict__ g, const float* __restrict__ be,
    const float* __restrict__ mu, const float* __restrict__ rs)
{
    const int L = L_;
    __shared__ float As[16][128];
    __shared__ float Ws[16][132];   // +4 pad: write bank = (4k+n)%32
    int tid = threadIdx.x;
    int b  = blockIdx.z;
    int l0 = blockIdx.x * 128;
    int n0 = blockIdx.y * 128;
    const float* Ab = A + (size_t)b * aBatch;
    float acc[8][8];
#pragma unroll
    for (int j = 0; j < 8; j++)
#pragma unroll
        for (int i = 0; i < 8; i++) acc[j][i] = 0.f;
    int tl = tid & 15, tn = tid >> 4;

    for (int k0 = 0; k0 < K; k0 += 16) {
        // A tile: 16 x 128
#pragma unroll
        for (int i = 0; i < 8; i++) {
            int idx = i * 256 + tid;
            int k = idx >> 7, l = idx & 127;
            float v = Ab[(size_t)(k0 + k) * L + l0 + l];
            if (ACT == 2) {
                float m = mu[b * L + l0 + l];
                float r = rs[b * L + l0 + l];
                v = (v - m) * r * g[k0 + k] + be[k0 + k];
            }
            As[k][l] = v;
        }
        // W tile: (128 n) x (16 k), stored transposed Ws[k][n]
#pragma unroll
        for (int i = 0; i < 8; i++) {
            int idx = i * 256 + tid;
            int n = idx >> 4, k = idx & 15;
            float v = 0.f;
            if (N % 128 == 0 || n0 + n < N)
                v = Wm[(size_t)(n0 + n) * K + k0 + k];
            Ws[k][n] = v;
        }
        __syncthreads();
#pragma unroll
        for (int k = 0; k < 16; k++) {
            float4 a0 = *(const float4*)&As[k][tl * 8];
            float4 a1 = *(const float4*)&As[k][tl * 8 + 4];
            float4 w0 = *(const float4*)&Ws[k][tn * 8];
            float4 w1 = *(const float4*)&Ws[k][tn * 8 + 4];
            float av[8] = {a0.x, a0.y, a0.z, a0.w, a1.x, a1.y, a1.z, a1.w};
            float wv[8] = {w0.x, w0.y, w0.z, w0.w, w1.x, w1.y, w1.z, w1.w};
#pragma unroll
            for (int j = 0; j < 8; j++)
#pragma unroll
                for (int i = 0; i < 8; i++)
                    acc[j][i] += wv[j] * av[i];
        }
        __syncthreads();
    }
    // epilogue
#pragma unroll
    for (int j = 0; j < 8; j++) {
        int n = n0 + tn * 8 + j;
        if (N % 128 != 0 && n >= N) continue;
        float bsn = (ACT == 1) ? bias[n] : 0.f;
        float4 o0, o1;
        float* po = &o0.x;
#pragma unroll
        for (int i = 0; i < 4; i++) {
            float v = acc[j][i];
            if (ACT == 1) v = softplus_f(v + bsn);
            po[i] = v;
        }
        po = &o1.x;
#pragma unroll
        for (int i = 0; i < 4; i++) {
            float v = acc[j][4 + i];
            if (ACT == 1) v = softplus_f(v + bsn);
            po[i] = v;
        }
        size_t off = ((size_t)b * N + n) * L + l0 + tl * 8;
        *(float4*)&C[off]     = o0;
        *(float4*)&C[off + 4] = o1;
    }
}

// 64x64 tile, 4x4 micro-tile variant (for small-N / small-K GEMMs)
template<int K, int N, int ACT>
__global__ __launch_bounds__(256) void gemm64(
    const float* __restrict__ A, int aBatch,
    const float* __restrict__ Wm,
    float* __restrict__ C,
    const float* __restrict__ bias)
{
    const int L = L_;
    __shared__ float As[16][64];
    __shared__ float Ws[16][68];
    int tid = threadIdx.x;
    int b  = blockIdx.z;
    int l0 = blockIdx.x * 64;
    int n0 = blockIdx.y * 64;
    const float* Ab = A + (size_t)b * aBatch;
    float acc[4][4];
#pragma unroll
    for (int j = 0; j < 4; j++)
#pragma unroll
        for (int i = 0; i < 4; i++) acc[j][i] = 0.f;
    int tl = tid & 15, tn = tid >> 4;

    for (int k0 = 0; k0 < K; k0 += 16) {
#pragma unroll
        for (int i = 0; i < 4; i++) {
            int idx = i * 256 + tid;
            int k = idx >> 6, l = idx & 63;
            As[k][l] = Ab[(size_t)(k0 + k) * L + l0 + l];
        }
#pragma unroll
        for (int i = 0; i < 4; i++) {
            int idx = i * 256 + tid;
            int n = idx >> 4, k = idx & 15;
            float v = 0.f;
            if (N % 64 == 0 || n0 + n < N)
                v = Wm[(size_t)(n0 + n) * K + k0 + k];
            Ws[k][n] = v;
        }
        __syncthreads();
#pragma unroll
        for (int k = 0; k < 16; k++) {
            float4 a4 = *(const float4*)&As[k][tl * 4];
            float4 w4 = *(const float4*)&Ws[k][tn * 4];
            float av[4] = {a4.x, a4.y, a4.z, a4.w};
            float wv[4] = {w4.x, w4.y, w4.z, w4.w};
#pragma unroll
            for (int j = 0; j < 4; j++)
#pragma unroll
                for (int i = 0; i < 4; i++)
                    acc[j][i] += wv[j] * av[i];
        }
        __syncthreads();
    }
#pragma unroll
    for (int j = 0; j < 4; j++) {
        int n = n0 + tn * 4 + j;
        if (N % 64 != 0 && n >= N) continue;
        float bsn = (ACT == 1) ? bias[n] : 0.f;
        float4 o;
        float* po = &o.x;
#pragma unroll
        for (int i = 0; i < 4; i++) {
            float v = acc[j][i];
            if (ACT == 1) v = softplus_f(v + bsn);
            po[i] = v;
        }
        *(float4*)&C[((size_t)b * N + n) * L + l0 + tl * 4] = o;
    }
}

// ---------------------------------------------------------------------------
// Depthwise 3x3 conv (pad 1) + bias + SiLU. One block per (b, d) plane.
// ---------------------------------------------------------------------------
__global__ __launch_bounds__(256) void conv_silu(
    const float* __restrict__ x, const float* __restrict__ wc,
    const float* __restrict__ bias, float* __restrict__ u)
{
    int d = blockIdx.x, b = blockIdx.y;
    __shared__ float t[66 * 66];
    const float* xp = x + ((size_t)b * DI_ + d) * (size_t)L_;
    int tid = threadIdx.x;
    for (int idx = tid; idx < 66 * 66; idx += 256) {
        int r = idx / 66, c = idx - r * 66;
        int h = r - 1, w2 = c - 1;
        float v = 0.f;
        if (h >= 0 && h < 64 && w2 >= 0 && w2 < 64) v = xp[h * 64 + w2];
        t[idx] = v;
    }
    __syncthreads();
    float w9[9];
#pragma unroll
    for (int i = 0; i < 9; i++) w9[i] = wc[d * 9 + i];
    float bi = bias[d];
    float* up = u + ((size_t)b * DI_ + d) * (size_t)L_;
#pragma unroll
    for (int it = 0; it < 16; it++) {
        int p = it * 256 + tid;
        int h = p >> 6, c = p & 63;
        float s = 0.f;
#pragma unroll
        for (int kh = 0; kh < 3; kh++)
#pragma unroll
            for (int kw = 0; kw < 3; kw++)
                s += t[(h + kh) * 66 + (c + kw)] * w9[kh * 3 + kw];
        s += bi;
        up[p] = silu_f(s);
    }
}

// ---------------------------------------------------------------------------
// Selective scan. One block per (b, d). 256 threads x 16-elem chunks = L=4096.
// n=4 independent scalar recurrences: s_l = exp(delta_l*A_n)*s_{l-1} + delta_l*u_l*B_l[n]
// y_l = sum_n s_l[n]*C_l[n] + D*u_l.  Writes y in-place over delta.
// ---------------------------------------------------------------------------
__global__ __launch_bounds__(256) void scan_kernel(
    float* __restrict__ dly,          // (B, DI, L): delta in, y out
    const float* __restrict__ u,      // (B, DI, L)
    const float* __restrict__ xdbl,   // (B, 56, L); rows 48..51 = B, 52..55 = C
    const float* __restrict__ A_log,  // (DI, 4)
    const float* __restrict__ Dp)     // (DI)
{
    const int L = L_;
    int d = blockIdx.x, b = blockIdx.y;
    int tid = threadIdx.x;
    int lane = tid & 63, wv = tid >> 6;
    size_t rowoff = ((size_t)b * DI_ + d) * (size_t)L + tid * 16;
    float dl[16], uu[16];
#pragma unroll
    for (int i = 0; i < 4; i++) {
        *(float4*)&dl[i * 4] = *(const float4*)&dly[rowoff + i * 4];
        *(float4*)&uu[i * 4] = *(const float4*)&u[rowoff + i * 4];
    }
    float An[4];
#pragma unroll
    for (int n = 0; n < 4; n++) An[n] = -expf(A_log[d * 4 + n]);
    float Dd = Dp[d];
    const float* xb = xdbl + (size_t)b * XD_ * L + tid * 16;

    // pass 1: per-thread chunk summaries (a_prod, s_partial) per state n
    float la[4], ls[4];
#pragma unroll
    for (int n = 0; n < 4; n++) {
        float Bv[16];
#pragma unroll
        for (int i = 0; i < 4; i++)
            *(float4*)&Bv[i * 4] = *(const float4*)&xb[(size_t)(R_ + n) * L + i * 4];
        float aa = 1.f, ss = 0.f;
#pragma unroll
        for (int i = 0; i < 16; i++) {
            float ai = expf(dl[i] * An[n]);
            ss = ai * ss + dl[i] * uu[i] * Bv[i];
            aa *= ai;
        }
        la[n] = aa; ls[n] = ss;
    }
    // wave-level inclusive scan (combine(prev,cur) = (ap*ac, ac*sp+sc))
#pragma unroll
    for (int off = 1; off < 64; off <<= 1) {
#pragma unroll
        for (int n = 0; n < 4; n++) {
            float pa = __shfl_up(la[n], off);
            float ps = __shfl_up(ls[n], off);
            if (lane >= off) {
                ls[n] = ls[n] + la[n] * ps;
                la[n] = la[n] * pa;
            }
        }
    }
    // exclusive within wave
    float ea[4], es[4];
#pragma unroll
    for (int n = 0; n < 4; n++) {
        ea[n] = __shfl_up(la[n], 1);
        es[n] = __shfl_up(ls[n], 1);
        if (lane == 0) { ea[n] = 1.f; es[n] = 0.f; }
    }
    __shared__ float wsum[4][8];
    if (lane == 63) {
#pragma unroll
        for (int n = 0; n < 4; n++) { wsum[wv][n] = la[n]; wsum[wv][4 + n] = ls[n]; }
    }
    __syncthreads();
    float carry[4];
#pragma unroll
    for (int n = 0; n < 4; n++) {
        float wss = 0.f;
        for (int w2 = 0; w2 < wv; w2++) {
            float a2 = wsum[w2][n], s2 = wsum[w2][4 + n];
            wss = a2 * wss + s2;
        }
        carry[n] = ea[n] * wss + es[n];
    }
    // pass 2: rescan chunk with carry, accumulate y
    float yv[16];
#pragma unroll
    for (int i = 0; i < 16; i++) yv[i] = Dd * uu[i];
#pragma unroll
    for (int n = 0; n < 4; n++) {
        float Bv[16], Cv[16];
#pragma unroll
        for (int i = 0; i < 4; i++) {
            *(float4*)&Bv[i * 4] = *(const float4*)&xb[(size_t)(R_ + n) * L + i * 4];
            *(float4*)&Cv[i * 4] = *(const float4*)&xb[(size_t)(R_ + 4 + n) * L + i * 4];
        }
        float s = carry[n];
#pragma unroll
        for (int i = 0; i < 16; i++) {
            float ai = expf(dl[i] * An[n]);
            s = ai * s + dl[i] * uu[i] * Bv[i];
            yv[i] += s * Cv[i];
        }
    }
#pragma unroll
    for (int i = 0; i < 4; i++)
        *(float4*)&dly[rowoff + i * 4] = *(const float4*)&yv[i * 4];
}

// ---------------------------------------------------------------------------
// LayerNorm stats over the d (channel) axis of y (B, DI, L).
// Block = 32 l-positions x 8 d-groups.
// ---------------------------------------------------------------------------
__global__ __launch_bounds__(256) void ln_stats(
    const float* __restrict__ y, float* __restrict__ mu, float* __restrict__ rs)
{
    int tid = threadIdx.x;
    int lsub = tid & 31, dg = tid >> 5;
    int l = blockIdx.x * 32 + lsub;
    int b = blockIdx.y;
    const float* yp = y + (size_t)b * DI_ * L_ + l;
    float s = 0.f, s2 = 0.f;
    for (int d = dg; d < DI_; d += 8) {
        float v = yp[(size_t)d * L_];
        s += v; s2 += v * v;
    }
    __shared__ float sh[2][8][32];
    sh[0][dg][lsub] = s; sh[1][dg][lsub] = s2;
    __syncthreads();
    if (dg == 0) {
#pragma unroll
        for (int g2 = 1; g2 < 8; g2++) { s += sh[0][g2][lsub]; s2 += sh[1][g2][lsub]; }
        const float inv = 1.f / DI_;
        float m = s * inv;
        float var = s2 * inv - m * m;
        mu[b * L_ + l] = m;
        rs[b * L_ + l] = rsqrtf(var + 1e-5f);
    }
}

extern "C" void kernel_launch(void* const* d_in, const int* in_sizes, int n_in,
                              void* d_out, int out_size, void* d_ws, size_t ws_size,
                              hipStream_t stream)
{
    const float* hidden = (const float*)d_in[0];   // (B, DM, H, W)
    const float* in_w   = (const float*)d_in[1];   // (DI, DM)
    const float* conv_w = (const float*)d_in[2];   // (DI, 1, 3, 3)
    const float* conv_b = (const float*)d_in[3];   // (DI)
    const float* xp_w   = (const float*)d_in[4];   // (56, DI)
    const float* dt_w   = (const float*)d_in[5];   // (1, DI, 48)
    const float* dt_b   = (const float*)d_in[6];   // (1, DI)
    const float* A_log  = (const float*)d_in[7];   // (1, DI, 4)
    const float* Dp     = (const float*)d_in[8];   // (1, DI)
    const float* ln_g   = (const float*)d_in[9];   // (DI)
    const float* ln_b   = (const float*)d_in[10];  // (DI)
    const float* out_w  = (const float*)d_in[11];  // (DM, DI)
    float* out = (float*)d_out;                    // (B, DM, H, W) == (B, DM, L)

    float* big1 = (float*)d_ws;                    // x -> delta -> y (in place)
    float* big2 = big1 + (size_t)B_ * DI_ * L_;    // u (post conv+silu)
    float* xdbl = big2 + (size_t)B_ * DI_ * L_;    // (B, 56, L)
    float* mu   = xdbl + (size_t)B_ * XD_ * L_;    // (B, L)
    float* rs   = mu + (size_t)B_ * L_;            // (B, L)

    // 1. in_proj: x[b][d][l] = sum_c hidden[b][c][l] * in_w[d][c]
    gemm128<DM_, DI_, 0><<<dim3(L_ / 128, DI_ / 128, B_), 256, 0, stream>>>(
        hidden, DM_ * L_, in_w, big1, nullptr, nullptr, nullptr, nullptr, nullptr);

    // 2. depthwise conv 3x3 + SiLU -> u
    conv_silu<<<dim3(DI_, B_), 256, 0, stream>>>(big1, conv_w, conv_b, big2);

    // 3. x_proj: xdbl[b][j][l] = sum_d u[b][d][l] * xp_w[j][d]
    gemm64<DI_, XD_, 0><<<dim3(L_ / 64, 1, B_), 256, 0, stream>>>(
        big2, DI_ * L_, xp_w, xdbl, nullptr);

    // 4. delta: softplus(sum_r xdbl[b][r][l] * dt_w[d][r] + dt_b[d]) -> big1
    gemm64<R_, DI_, 1><<<dim3(L_ / 64, DI_ / 64, B_), 256, 0, stream>>>(
        xdbl, XD_ * L_, dt_w, big1, dt_b);

    // 5. selective scan: y (in place over delta in big1)
    scan_kernel<<<dim3(DI_, B_), 256, 0, stream>>>(big1, big2, xdbl, A_log, Dp);

    // 6. LayerNorm stats
    ln_stats<<<dim3(L_ / 32, B_), 256, 0, stream>>>(big1, mu, rs);

    // 7. out_proj with LN fused on A-load -> d_out
    gemm128<DI_, DM_, 2><<<dim3(L_ / 128, DM_ / 128, B_), 256, 0, stream>>>(
        big1, DI_ * L_, out_w, out, nullptr, ln_g, ln_b, mu, rs);
}

// Round 2
// 673.727 us; speedup vs baseline: 1.6632x; 1.6632x over previous
//
#include <hip/hip_runtime.h>
#include <math.h>

#define B_   2
#define DM_  768
#define L_   4096
#define DI_  1536
#define NS_  4
#define R_   48
#define XD_  56   // R + 2*NS

typedef __attribute__((ext_vector_type(8))) short s16x8;
typedef __attribute__((ext_vector_type(4))) float f32x4;
typedef __attribute__((ext_vector_type(8))) unsigned short us8;
typedef __attribute__((ext_vector_type(4))) unsigned short us4;

__device__ __forceinline__ float softplus_f(float x) {
    return fmaxf(x, 0.f) + log1pf(expf(-fabsf(x)));
}
__device__ __forceinline__ float silu_f(float x) {
    return x / (1.f + expf(-x));
}

// round-to-nearest bf16 (inputs finite)
__device__ __forceinline__ unsigned short bf16_rn(float v) {
    unsigned u = __float_as_uint(v);
    u += 0x7FFFu + ((u >> 16) & 1u);
    return (unsigned short)(u >> 16);
}
// v ~= hi + lo with ~16-bit effective mantissa
__device__ __forceinline__ void split2(float v, unsigned short& h, unsigned short& l) {
    h = bf16_rn(v);
    float fh = __uint_as_float(((unsigned)h) << 16);
    l = bf16_rn(v - fh);   // residual is exact in fp32
}

__device__ __forceinline__ void cp16(const void* g, void* l) {
    __builtin_amdgcn_global_load_lds(
        (const __attribute__((address_space(1))) unsigned int*)g,
        (__attribute__((address_space(3))) unsigned int*)l, 16, 0, 0);
}

// ---------------------------------------------------------------------------
// Split a weight matrix (N,K) fp32 row-major -> flat bf16 hi/lo (same layout).
// ---------------------------------------------------------------------------
__global__ __launch_bounds__(256) void split_w(const float* __restrict__ W,
    unsigned short* __restrict__ Wh, unsigned short* __restrict__ Wl, int n4)
{
    int id = blockIdx.x * 256 + threadIdx.x;
    if (id >= n4) return;
    float4 v = *(const float4*)(W + (size_t)id * 4);
    us4 h, l;
    unsigned short hh, ll;
    split2(v.x, hh, ll); h[0] = hh; l[0] = ll;
    split2(v.y, hh, ll); h[1] = hh; l[1] = ll;
    split2(v.z, hh, ll); h[2] = hh; l[2] = ll;
    split2(v.w, hh, ll); h[3] = hh; l[3] = ll;
    *(us4*)(Wh + (size_t)id * 4) = h;
    *(us4*)(Wl + (size_t)id * 4) = l;
}

// ---------------------------------------------------------------------------
// Pack activations X (B,K,L) fp32 l-major into k-contiguous padded bf16 tiles:
// per (b, l-tile of 128, k-tile of 32): 128 rows x (32 bf16 + 8 pad) = 80B/row
// = 10240B/tile. Optional fused LayerNorm (over k) on load.
// Tile base (ushorts): ((b*32 + lt)*KT + kt) * 5120; elem: + l*40 + k.
// ---------------------------------------------------------------------------
template<int K, bool LN>
__global__ __launch_bounds__(256) void pack_x(
    const float* __restrict__ X,
    unsigned short* __restrict__ Xh, unsigned short* __restrict__ Xl,
    const float* __restrict__ mu, const float* __restrict__ rs,
    const float* __restrict__ g, const float* __restrict__ be)
{
    const int KT = K / 32;
    int kt = blockIdx.x, lt = blockIdx.y, b = blockIdx.z;
    __shared__ float t[32][133];
    int tid = threadIdx.x;
    const float* Xp = X + ((size_t)b * K + kt * 32) * L_ + lt * 128;
#pragma unroll
    for (int i = 0; i < 4; ++i) {
        int id = i * 256 + tid;          // 1024 float4 chunks
        int k = id >> 5, f4 = id & 31;
        float4 v = *(const float4*)(Xp + (size_t)k * L_ + f4 * 4);
        t[k][f4 * 4]     = v.x;
        t[k][f4 * 4 + 1] = v.y;
        t[k][f4 * 4 + 2] = v.z;
        t[k][f4 * 4 + 3] = v.w;
    }
    __syncthreads();
    size_t tb = ((size_t)(b * 32 + lt) * KT + kt) * 5120;
    unsigned short* ph = Xh + tb;
    unsigned short* pl = Xl + tb;
#pragma unroll
    for (int i = 0; i < 2; ++i) {
        int id = i * 256 + tid;          // 512 16B chunks
        int l = id >> 2, kbv = id & 3;
        float m = 0.f, r = 1.f;
        if (LN) { m = mu[b * L_ + lt * 128 + l]; r = rs[b * L_ + lt * 128 + l]; }
        us8 hv, lv;
#pragma unroll
        for (int j = 0; j < 8; ++j) {
            int k = kbv * 8 + j;
            float v = t[k][l];
            if (LN) v = (v - m) * r * g[kt * 32 + k] + be[kt * 32 + k];
            unsigned short hh, ll;
            split2(v, hh, ll);
            hv[j] = hh; lv[j] = ll;
        }
        *(us8*)(ph + l * 40 + kbv * 8) = hv;
        *(us8*)(pl + l * 40 + kbv * 8) = lv;
    }
}

// ---------------------------------------------------------------------------
// MFMA GEMM: C[b][n][l] = sum_k W[n][k] * X[b][k][l], fp32 out.
// bf16 hi/lo 3-term emulation: Wh*Xh + Wh*Xl + Wl*Xh (fp32 accumulate).
// Block: BN(=MBF*32) x 128l, 4 waves (2x2), BK=32 (one 16x16x32 MFMA in K).
// X tiles staged to LDS via global_load_lds(16B) from the packed layout.
// W fragments loaded per-lane straight from global (L2/L3-resident).
// ---------------------------------------------------------------------------
template<int K, int MBF>
__global__ __launch_bounds__(256) void gemm_mfma(
    const unsigned short* __restrict__ Wh, const unsigned short* __restrict__ Wl,
    const unsigned short* __restrict__ Xh, const unsigned short* __restrict__ Xl,
    float* __restrict__ C, int N)
{
    const int KT = K / 32;
    const int BN = MBF * 32;
    __shared__ unsigned short lds[10240];   // [0,5120) Xh tile | [5120,10240) Xl tile
    int tid = threadIdx.x;
    int lt = blockIdx.x, nt = blockIdx.y, b = blockIdx.z;
    int lane = tid & 63, w = tid >> 6;
    int wn = (w >> 1) * (MBF * 16), wl = (w & 1) * 64;
    int row = lane & 15, kb = lane >> 4;

    const unsigned short* xh_t = Xh + ((size_t)(b * 32 + lt) * KT) * 5120;
    const unsigned short* xl_t = Xl + ((size_t)(b * 32 + lt) * KT) * 5120;
    const unsigned short* wh_p = Wh + (size_t)(nt * BN + wn + row) * K + kb * 8;
    const unsigned short* wl_p = Wl + (size_t)(nt * BN + wn + row) * K + kb * 8;

    f32x4 acc[MBF][4];
#pragma unroll
    for (int m = 0; m < MBF; m++)
#pragma unroll
        for (int l2 = 0; l2 < 4; l2++) acc[m][l2] = (f32x4){0.f, 0.f, 0.f, 0.f};

    for (int kt = 0; kt < KT; ++kt) {
        const unsigned short* sh = xh_t + (size_t)kt * 5120;
        const unsigned short* sl = xl_t + (size_t)kt * 5120;
#pragma unroll
        for (int i = 0; i < 3; ++i) {
            int slot = i * 256 + tid;               // 640 x 16B per tile
            if (slot < 640) {
                int lbase = (i * 256 + (tid & 192)) * 8;   // wave-uniform LDS base
                cp16(sh + slot * 8, &lds[lbase]);
                cp16(sl + slot * 8, &lds[5120 + lbase]);
            }
        }
        s16x8 ah[MBF], al[MBF];
#pragma unroll
        for (int m = 0; m < MBF; m++) {
            ah[m] = *(const s16x8*)(wh_p + (size_t)m * 16 * K + kt * 32);
            al[m] = *(const s16x8*)(wl_p + (size_t)m * 16 * K + kt * 32);
        }
        __syncthreads();    // drains vmcnt -> LDS tile + W frags ready
        s16x8 bh[4], bl[4];
#pragma unroll
        for (int l2 = 0; l2 < 4; l2++) {
            int off = (wl + l2 * 16 + row) * 40 + kb * 8;
            bh[l2] = *(const s16x8*)&lds[off];
            bl[l2] = *(const s16x8*)&lds[5120 + off];
        }
#pragma unroll
        for (int m = 0; m < MBF; m++)
#pragma unroll
            for (int l2 = 0; l2 < 4; l2++) {
                acc[m][l2] = __builtin_amdgcn_mfma_f32_16x16x32_bf16(ah[m], bh[l2], acc[m][l2], 0, 0, 0);
                acc[m][l2] = __builtin_amdgcn_mfma_f32_16x16x32_bf16(ah[m], bl[l2], acc[m][l2], 0, 0, 0);
                acc[m][l2] = __builtin_amdgcn_mfma_f32_16x16x32_bf16(al[m], bh[l2], acc[m][l2], 0, 0, 0);
            }
        __syncthreads();    // all waves done reading before next overwrite
    }
    float* Cp = C + ((size_t)b * N + nt * BN) * L_ + (size_t)lt * 128;
#pragma unroll
    for (int m = 0; m < MBF; m++)
#pragma unroll
        for (int l2 = 0; l2 < 4; l2++) {
            int lcol = wl + l2 * 16 + row;
#pragma unroll
            for (int j = 0; j < 4; j++) {
                int nrow = wn + m * 16 + kb * 4 + j;   // C/D: col=lane&15, row=(lane>>4)*4+j
                Cp[(size_t)nrow * L_ + lcol] = acc[m][l2][j];
            }
        }
}

// ---------------------------------------------------------------------------
// 64x64 fp32 VALU GEMM (small K or N): C[b][n][l] = act(sum_k A[b][k][l]*W[n][k])
// ---------------------------------------------------------------------------
template<int K, int N, int ACT>
__global__ __launch_bounds__(256) void gemm64(
    const float* __restrict__ A, int aBatch,
    const float* __restrict__ Wm,
    float* __restrict__ C,
    const float* __restrict__ bias)
{
    const int L = L_;
    __shared__ float As[16][64];
    __shared__ float Ws[16][68];
    int tid = threadIdx.x;
    int b  = blockIdx.z;
    int l0 = blockIdx.x * 64;
    int n0 = blockIdx.y * 64;
    const float* Ab = A + (size_t)b * aBatch;
    float acc[4][4];
#pragma unroll
    for (int j = 0; j < 4; j++)
#pragma unroll
        for (int i = 0; i < 4; i++) acc[j][i] = 0.f;
    int tl = tid & 15, tn = tid >> 4;

    for (int k0 = 0; k0 < K; k0 += 16) {
#pragma unroll
        for (int i = 0; i < 4; i++) {
            int idx = i * 256 + tid;
            int k = idx >> 6, l = idx & 63;
            As[k][l] = Ab[(size_t)(k0 + k) * L + l0 + l];
        }
#pragma unroll
        for (int i = 0; i < 4; i++) {
            int idx = i * 256 + tid;
            int n = idx >> 4, k = idx & 15;
            float v = 0.f;
            if (N % 64 == 0 || n0 + n < N)
                v = Wm[(size_t)(n0 + n) * K + k0 + k];
            Ws[k][n] = v;
        }
        __syncthreads();
#pragma unroll
        for (int k = 0; k < 16; k++) {
            float4 a4 = *(const float4*)&As[k][tl * 4];
            float4 w4 = *(const float4*)&Ws[k][tn * 4];
            float av[4] = {a4.x, a4.y, a4.z, a4.w};
            float wv[4] = {w4.x, w4.y, w4.z, w4.w};
#pragma unroll
            for (int j = 0; j < 4; j++)
#pragma unroll
                for (int i = 0; i < 4; i++)
                    acc[j][i] += wv[j] * av[i];
        }
        __syncthreads();
    }
#pragma unroll
    for (int j = 0; j < 4; j++) {
        int n = n0 + tn * 4 + j;
        if (N % 64 != 0 && n >= N) continue;
        float bsn = (ACT == 1) ? bias[n] : 0.f;
        float4 o;
        float* po = &o.x;
#pragma unroll
        for (int i = 0; i < 4; i++) {
            float v = acc[j][i];
            if (ACT == 1) v = softplus_f(v + bsn);
            po[i] = v;
        }
        *(float4*)&C[((size_t)b * N + n) * L + l0 + tl * 4] = o;
    }
}

// ---------------------------------------------------------------------------
// Depthwise 3x3 conv (pad 1) + bias + SiLU. One block per (b, d) plane.
// ---------------------------------------------------------------------------
__global__ __launch_bounds__(256) void conv_silu(
    const float* __restrict__ x, const float* __restrict__ wc,
    const float* __restrict__ bias, float* __restrict__ u)
{
    int d = blockIdx.x, b = blockIdx.y;
    __shared__ float t[66 * 66];
    const float* xp = x + ((size_t)b * DI_ + d) * (size_t)L_;
    int tid = threadIdx.x;
    for (int idx = tid; idx < 66 * 66; idx += 256) {
        int r = idx / 66, c = idx - r * 66;
        int h = r - 1, w2 = c - 1;
        float v = 0.f;
        if (h >= 0 && h < 64 && w2 >= 0 && w2 < 64) v = xp[h * 64 + w2];
        t[idx] = v;
    }
    __syncthreads();
    float w9[9];
#pragma unroll
    for (int i = 0; i < 9; i++) w9[i] = wc[d * 9 + i];
    float bi = bias[d];
    float* up = u + ((size_t)b * DI_ + d) * (size_t)L_;
#pragma unroll
    for (int it = 0; it < 16; it++) {
        int p = it * 256 + tid;
        int h = p >> 6, c = p & 63;
        float s = 0.f;
#pragma unroll
        for (int kh = 0; kh < 3; kh++)
#pragma unroll
            for (int kw = 0; kw < 3; kw++)
                s += t[(h + kh) * 66 + (c + kw)] * w9[kh * 3 + kw];
        s += bi;
        up[p] = silu_f(s);
    }
}

// ---------------------------------------------------------------------------
// Selective scan. One block per (b, d). 256 threads x 16-elem chunks = L=4096.
// ---------------------------------------------------------------------------
__global__ __launch_bounds__(256) void scan_kernel(
    float* __restrict__ dly,          // (B, DI, L): delta in, y out
    const float* __restrict__ u,      // (B, DI, L)
    const float* __restrict__ xdbl,   // (B, 56, L); rows 48..51 = B, 52..55 = C
    const float* __restrict__ A_log,  // (DI, 4)
    const float* __restrict__ Dp)     // (DI)
{
    const int L = L_;
    int d = blockIdx.x, b = blockIdx.y;
    int tid = threadIdx.x;
    int lane = tid & 63, wv = tid >> 6;
    size_t rowoff = ((size_t)b * DI_ + d) * (size_t)L + tid * 16;
    float dl[16], uu[16];
#pragma unroll
    for (int i = 0; i < 4; i++) {
        *(float4*)&dl[i * 4] = *(const float4*)&dly[rowoff + i * 4];
        *(float4*)&uu[i * 4] = *(const float4*)&u[rowoff + i * 4];
    }
    float An[4];
#pragma unroll
    for (int n = 0; n < 4; n++) An[n] = -expf(A_log[d * 4 + n]);
    float Dd = Dp[d];
    const float* xb = xdbl + (size_t)b * XD_ * L + tid * 16;

    float la[4], ls[4];
#pragma unroll
    for (int n = 0; n < 4; n++) {
        float Bv[16];
#pragma unroll
        for (int i = 0; i < 4; i++)
            *(float4*)&Bv[i * 4] = *(const float4*)&xb[(size_t)(R_ + n) * L + i * 4];
        float aa = 1.f, ss = 0.f;
#pragma unroll
        for (int i = 0; i < 16; i++) {
            float ai = expf(dl[i] * An[n]);
            ss = ai * ss + dl[i] * uu[i] * Bv[i];
            aa *= ai;
        }
        la[n] = aa; ls[n] = ss;
    }
#pragma unroll
    for (int off = 1; off < 64; off <<= 1) {
#pragma unroll
        for (int n = 0; n < 4; n++) {
            float pa = __shfl_up(la[n], off);
            float ps = __shfl_up(ls[n], off);
            if (lane >= off) {
                ls[n] = ls[n] + la[n] * ps;
                la[n] = la[n] * pa;
            }
        }
    }
    float ea[4], es[4];
#pragma unroll
    for (int n = 0; n < 4; n++) {
        ea[n] = __shfl_up(la[n], 1);
        es[n] = __shfl_up(ls[n], 1);
        if (lane == 0) { ea[n] = 1.f; es[n] = 0.f; }
    }
    __shared__ float wsum[4][8];
    if (lane == 63) {
#pragma unroll
        for (int n = 0; n < 4; n++) { wsum[wv][n] = la[n]; wsum[wv][4 + n] = ls[n]; }
    }
    __syncthreads();
    float carry[4];
#pragma unroll
    for (int n = 0; n < 4; n++) {
        float wss = 0.f;
        for (int w2 = 0; w2 < wv; w2++) {
            float a2 = wsum[w2][n], s2 = wsum[w2][4 + n];
            wss = a2 * wss + s2;
        }
        carry[n] = ea[n] * wss + es[n];
    }
    float yv[16];
#pragma unroll
    for (int i = 0; i < 16; i++) yv[i] = Dd * uu[i];
#pragma unroll
    for (int n = 0; n < 4; n++) {
        float Bv[16], Cv[16];
#pragma unroll
        for (int i = 0; i < 4; i++) {
            *(float4*)&Bv[i * 4] = *(const float4*)&xb[(size_t)(R_ + n) * L + i * 4];
            *(float4*)&Cv[i * 4] = *(const float4*)&xb[(size_t)(R_ + 4 + n) * L + i * 4];
        }
        float s = carry[n];
#pragma unroll
        for (int i = 0; i < 16; i++) {
            float ai = expf(dl[i] * An[n]);
            s = ai * s + dl[i] * uu[i] * Bv[i];
            yv[i] += s * Cv[i];
        }
    }
#pragma unroll
    for (int i = 0; i < 4; i++)
        *(float4*)&dly[rowoff + i * 4] = *(const float4*)&yv[i * 4];
}

// ---------------------------------------------------------------------------
// LayerNorm stats over the d (channel) axis of y (B, DI, L).
// ---------------------------------------------------------------------------
__global__ __launch_bounds__(256) void ln_stats(
    const float* __restrict__ y, float* __restrict__ mu, float* __restrict__ rs)
{
    int tid = threadIdx.x;
    int lsub = tid & 31, dg = tid >> 5;
    int l = blockIdx.x * 32 + lsub;
    int b = blockIdx.y;
    const float* yp = y + (size_t)b * DI_ * L_ + l;
    float s = 0.f, s2 = 0.f;
    for (int d = dg; d < DI_; d += 8) {
        float v = yp[(size_t)d * L_];
        s += v; s2 += v * v;
    }
    __shared__ float sh[2][8][32];
    sh[0][dg][lsub] = s; sh[1][dg][lsub] = s2;
    __syncthreads();
    if (dg == 0) {
#pragma unroll
        for (int g2 = 1; g2 < 8; g2++) { s += sh[0][g2][lsub]; s2 += sh[1][g2][lsub]; }
        const float inv = 1.f / DI_;
        float m = s * inv;
        float var = s2 * inv - m * m;
        mu[b * L_ + l] = m;
        rs[b * L_ + l] = rsqrtf(var + 1e-5f);
    }
}

extern "C" void kernel_launch(void* const* d_in, const int* in_sizes, int n_in,
                              void* d_out, int out_size, void* d_ws, size_t ws_size,
                              hipStream_t stream)
{
    const float* hidden = (const float*)d_in[0];   // (B, DM, H, W)
    const float* in_w   = (const float*)d_in[1];   // (DI, DM)
    const float* conv_w = (const float*)d_in[2];   // (DI, 1, 3, 3)
    const float* conv_b = (const float*)d_in[3];   // (DI)
    const float* xp_w   = (const float*)d_in[4];   // (56, DI)
    const float* dt_w   = (const float*)d_in[5];   // (1, DI, 48)
    const float* dt_b   = (const float*)d_in[6];   // (1, DI)
    const float* A_log  = (const float*)d_in[7];   // (1, DI, 4)
    const float* Dp     = (const float*)d_in[8];   // (1, DI)
    const float* ln_g   = (const float*)d_in[9];   // (DI)
    const float* ln_b   = (const float*)d_in[10];  // (DI)
    const float* out_w  = (const float*)d_in[11];  // (DM, DI)
    float* out = (float*)d_out;                    // (B, DM, L)

    const size_t BIG = (size_t)B_ * DI_ * L_;
    float* big1 = (float*)d_ws;                    // x -> delta -> y (in place)
    float* big2 = big1 + BIG;                      // u
    float* xdbl = big2 + BIG;                      // (B, 56, L)
    float* mu   = xdbl + (size_t)B_ * XD_ * L_;
    float* rs   = mu + (size_t)B_ * L_;
    unsigned short* pack = (unsigned short*)(rs + (size_t)B_ * L_);

    const size_t NK = (size_t)DI_ * DM_;                       // W elems (both GEMMs)
    const size_t XPK = (size_t)B_ * 32 * (DM_ / 32) * 5120;    // packed X ushorts
    const size_t YPK = (size_t)B_ * 32 * (DI_ / 32) * 5120;    // packed Y ushorts
    unsigned short* wh = pack;
    unsigned short* wlo = pack + NK;
    unsigned short* xh = pack + 2 * NK;

    // ---- phase 1: in_proj on MFMA ----
    split_w<<<(int)(NK / 4 / 256), 256, 0, stream>>>(in_w, wh, wlo, (int)(NK / 4));
    pack_x<DM_, false><<<dim3(DM_ / 32, 32, B_), 256, 0, stream>>>(
        hidden, xh, xh + XPK, nullptr, nullptr, nullptr, nullptr);
    gemm_mfma<DM_, 4><<<dim3(32, DI_ / 128, B_), 256, 0, stream>>>(
        wh, wlo, xh, xh + XPK, big1, DI_);

    // ---- middle: conv + x_proj + delta + scan + ln stats ----
    conv_silu<<<dim3(DI_, B_), 256, 0, stream>>>(big1, conv_w, conv_b, big2);
    gemm64<DI_, XD_, 0><<<dim3(L_ / 64, 1, B_), 256, 0, stream>>>(
        big2, DI_ * L_, xp_w, xdbl, nullptr);
    gemm64<R_, DI_, 1><<<dim3(L_ / 64, DI_ / 64, B_), 256, 0, stream>>>(
        xdbl, XD_ * L_, dt_w, big1, dt_b);
    scan_kernel<<<dim3(DI_, B_), 256, 0, stream>>>(big1, big2, xdbl, A_log, Dp);
    ln_stats<<<dim3(L_ / 32, B_), 256, 0, stream>>>(big1, mu, rs);

    // ---- phase 2: out_proj on MFMA (LN fused into pack) ----
    split_w<<<(int)(NK / 4 / 256), 256, 0, stream>>>(out_w, wh, wlo, (int)(NK / 4));
    unsigned short* yh = pack + 2 * NK;
    pack_x<DI_, true><<<dim3(DI_ / 32, 32, B_), 256, 0, stream>>>(
        big1, yh, yh + YPK, mu, rs, ln_g, ln_b);
    gemm_mfma<DI_, 2><<<dim3(32, DM_ / 64, B_), 256, 0, stream>>>(
        wh, wlo, yh, yh + YPK, out, DM_);
}

// Round 5
// 555.379 us; speedup vs baseline: 2.0177x; 1.2131x over previous
//
#include <hip/hip_runtime.h>
#include <math.h>

#define B_   2
#define DM_  768
#define L_   4096
#define DI_  1536
#define NS_  4
#define R_   48
#define XD_  56   // R + 2*NS

#define KSX_  12    // x_proj K splits
#define KCHX_ 128   // DI_ / KSX_

typedef __attribute__((ext_vector_type(8))) short s16x8;
typedef __attribute__((ext_vector_type(4))) float f32x4;
typedef __attribute__((ext_vector_type(8))) unsigned short us8;
typedef __attribute__((ext_vector_type(4))) unsigned short us4;

__device__ __forceinline__ float softplus_f(float x) {
    return fmaxf(x, 0.f) + log1pf(expf(-fabsf(x)));
}
__device__ __forceinline__ float silu_f(float x) {
    return x / (1.f + expf(-x));
}

// round-to-nearest bf16 (inputs finite)
__device__ __forceinline__ unsigned short bf16_rn(float v) {
    unsigned u = __float_as_uint(v);
    u += 0x7FFFu + ((u >> 16) & 1u);
    return (unsigned short)(u >> 16);
}
// v ~= hi + lo with ~16-bit effective mantissa
__device__ __forceinline__ void split2(float v, unsigned short& h, unsigned short& l) {
    h = bf16_rn(v);
    float fh = __uint_as_float(((unsigned)h) << 16);
    l = bf16_rn(v - fh);
}

__device__ __forceinline__ void cp16(const void* g, void* l) {
    __builtin_amdgcn_global_load_lds(
        (const __attribute__((address_space(1))) unsigned int*)g,
        (__attribute__((address_space(3))) unsigned int*)l, 16, 0, 0);
}

// ---------------------------------------------------------------------------
// Split a weight matrix (N,K) fp32 row-major -> flat bf16 hi/lo (same layout).
// ---------------------------------------------------------------------------
__global__ __launch_bounds__(256) void split_w(const float* __restrict__ W,
    unsigned short* __restrict__ Wh, unsigned short* __restrict__ Wl, int n4)
{
    int id = blockIdx.x * 256 + threadIdx.x;
    if (id >= n4) return;
    float4 v = *(const float4*)(W + (size_t)id * 4);
    us4 h, l;
    unsigned short hh, ll;
    split2(v.x, hh, ll); h[0] = hh; l[0] = ll;
    split2(v.y, hh, ll); h[1] = hh; l[1] = ll;
    split2(v.z, hh, ll); h[2] = hh; l[2] = ll;
    split2(v.w, hh, ll); h[3] = hh; l[3] = ll;
    *(us4*)(Wh + (size_t)id * 4) = h;
    *(us4*)(Wl + (size_t)id * 4) = l;
}

// ---------------------------------------------------------------------------
// Pack activations X (B,K,L) fp32 l-major into k-contiguous padded bf16 tiles:
// per (b, l-tile of 128, k-tile of 32): 128 rows x (32 bf16 + 8 pad) = 80B/row.
// Tile base (ushorts): ((b*32 + lt)*KT + kt) * 5120; elem: + l*40 + k.
// ---------------------------------------------------------------------------
template<int K, bool LN>
__global__ __launch_bounds__(256) void pack_x(
    const float* __restrict__ X,
    unsigned short* __restrict__ Xh, unsigned short* __restrict__ Xl,
    const float* __restrict__ mu, const float* __restrict__ rs,
    const float* __restrict__ g, const float* __restrict__ be)
{
    const int KT = K / 32;
    int kt = blockIdx.x, lt = blockIdx.y, b = blockIdx.z;
    __shared__ float t[32][133];
    int tid = threadIdx.x;
    const float* Xp = X + ((size_t)b * K + kt * 32) * L_ + lt * 128;
#pragma unroll
    for (int i = 0; i < 4; ++i) {
        int id = i * 256 + tid;
        int k = id >> 5, f4 = id & 31;
        float4 v = *(const float4*)(Xp + (size_t)k * L_ + f4 * 4);
        t[k][f4 * 4]     = v.x;
        t[k][f4 * 4 + 1] = v.y;
        t[k][f4 * 4 + 2] = v.z;
        t[k][f4 * 4 + 3] = v.w;
    }
    __syncthreads();
    size_t tb = ((size_t)(b * 32 + lt) * KT + kt) * 5120;
    unsigned short* ph = Xh + tb;
    unsigned short* pl = Xl + tb;
#pragma unroll
    for (int i = 0; i < 2; ++i) {
        int id = i * 256 + tid;
        int l = id >> 2, kbv = id & 3;
        float m = 0.f, r = 1.f;
        if (LN) { m = mu[b * L_ + lt * 128 + l]; r = rs[b * L_ + lt * 128 + l]; }
        us8 hv, lv;
#pragma unroll
        for (int j = 0; j < 8; ++j) {
            int k = kbv * 8 + j;
            float v = t[k][l];
            if (LN) v = (v - m) * r * g[kt * 32 + k] + be[kt * 32 + k];
            unsigned short hh, ll;
            split2(v, hh, ll);
            hv[j] = hh; lv[j] = ll;
        }
        *(us8*)(ph + l * 40 + kbv * 8) = hv;
        *(us8*)(pl + l * 40 + kbv * 8) = lv;
    }
}

// ---------------------------------------------------------------------------
// MFMA GEMM: C[b][n][l] = sum_k W[n][k] * X[b][k][l], fp32 out.
// bf16 hi/lo 3-term emulation: Wh*Xh + Wh*Xl + Wl*Xh (fp32 accumulate).
// XCD-chunked bijective swizzle, nt-fastest decode: all NT readers of one X
// tile land on the same XCD -> X fetched ~once per tile from HBM.
// ---------------------------------------------------------------------------
template<int K, int MBF>
__global__ __launch_bounds__(256) void gemm_mfma(
    const unsigned short* __restrict__ Wh, const unsigned short* __restrict__ Wl,
    const unsigned short* __restrict__ Xh, const unsigned short* __restrict__ Xl,
    float* __restrict__ C, int N)
{
    const int KT = K / 32;
    const int BN = MBF * 32;
    __shared__ unsigned short lds[10240];
    int tid = threadIdx.x;
    // --- XCD chunked swizzle (nwg = 32*NT*B, divisible by 8) ---
    int NT = gridDim.y;
    int nwg = 32 * NT * (int)gridDim.z;
    int bid = blockIdx.x + 32 * (blockIdx.y + NT * blockIdx.z);
    int cpx = nwg >> 3;
    int swz = (bid & 7) * cpx + (bid >> 3);
    int nt = swz % NT; int t2 = swz / NT;
    int lt = t2 & 31;  int b  = t2 >> 5;

    int lane = tid & 63, w = tid >> 6;
    int wn = (w >> 1) * (MBF * 16), wl = (w & 1) * 64;
    int row = lane & 15, kb = lane >> 4;

    const unsigned short* xh_t = Xh + ((size_t)(b * 32 + lt) * KT) * 5120;
    const unsigned short* xl_t = Xl + ((size_t)(b * 32 + lt) * KT) * 5120;
    const unsigned short* wh_p = Wh + (size_t)(nt * BN + wn + row) * K + kb * 8;
    const unsigned short* wl_p = Wl + (size_t)(nt * BN + wn + row) * K + kb * 8;

    f32x4 acc[MBF][4];
#pragma unroll
    for (int m = 0; m < MBF; m++)
#pragma unroll
        for (int l2 = 0; l2 < 4; l2++) acc[m][l2] = (f32x4){0.f, 0.f, 0.f, 0.f};

    for (int kt = 0; kt < KT; ++kt) {
        const unsigned short* sh = xh_t + (size_t)kt * 5120;
        const unsigned short* sl = xl_t + (size_t)kt * 5120;
#pragma unroll
        for (int i = 0; i < 3; ++i) {
            int slot = i * 256 + tid;
            if (slot < 640) {
                int lbase = (i * 256 + (tid & 192)) * 8;   // wave-uniform LDS base
                cp16(sh + slot * 8, &lds[lbase]);
                cp16(sl + slot * 8, &lds[5120 + lbase]);
            }
        }
        s16x8 ah[MBF], al[MBF];
#pragma unroll
        for (int m = 0; m < MBF; m++) {
            ah[m] = *(const s16x8*)(wh_p + (size_t)m * 16 * K + kt * 32);
            al[m] = *(const s16x8*)(wl_p + (size_t)m * 16 * K + kt * 32);
        }
        __syncthreads();
        s16x8 bh[4], bl[4];
#pragma unroll
        for (int l2 = 0; l2 < 4; l2++) {
            int off = (wl + l2 * 16 + row) * 40 + kb * 8;
            bh[l2] = *(const s16x8*)&lds[off];
            bl[l2] = *(const s16x8*)&lds[5120 + off];
        }
#pragma unroll
        for (int m = 0; m < MBF; m++)
#pragma unroll
            for (int l2 = 0; l2 < 4; l2++) {
                acc[m][l2] = __builtin_amdgcn_mfma_f32_16x16x32_bf16(ah[m], bh[l2], acc[m][l2], 0, 0, 0);
                acc[m][l2] = __builtin_amdgcn_mfma_f32_16x16x32_bf16(ah[m], bl[l2], acc[m][l2], 0, 0, 0);
                acc[m][l2] = __builtin_amdgcn_mfma_f32_16x16x32_bf16(al[m], bh[l2], acc[m][l2], 0, 0, 0);
            }
        __syncthreads();
    }
    float* Cp = C + ((size_t)b * N + nt * BN) * L_ + (size_t)lt * 128;
#pragma unroll
    for (int m = 0; m < MBF; m++)
#pragma unroll
        for (int l2 = 0; l2 < 4; l2++) {
            int lcol = wl + l2 * 16 + row;
#pragma unroll
            for (int j = 0; j < 4; j++) {
                int nrow = wn + m * 16 + kb * 4 + j;
                Cp[(size_t)nrow * L_ + lcol] = acc[m][l2][j];
            }
        }
}

// ---------------------------------------------------------------------------
// x_proj split-K stage 1: part[b][ks][n][l] = sum_{k in chunk} u[b][k][l]*W[n][k]
// 64l x 56n tile, K-chunk 128. Grid (L/64, KSX, B) = 1536 blocks.
// ---------------------------------------------------------------------------
__global__ __launch_bounds__(256) void xproj_sk(
    const float* __restrict__ u, const float* __restrict__ Wm,
    float* __restrict__ part)
{
    __shared__ float As[16][64];
    __shared__ float Ws[16][68];
    int tid = threadIdx.x;
    int l0 = blockIdx.x * 64;
    int ks = blockIdx.y;
    int b  = blockIdx.z;
    int kbase = ks * KCHX_;
    const float* Ab = u + (size_t)b * DI_ * L_;
    float acc[4][4];
#pragma unroll
    for (int j = 0; j < 4; j++)
#pragma unroll
        for (int i = 0; i < 4; i++) acc[j][i] = 0.f;
    int tl = tid & 15, tn = tid >> 4;

    for (int k0 = 0; k0 < KCHX_; k0 += 16) {
#pragma unroll
        for (int i = 0; i < 4; i++) {
            int idx = i * 256 + tid;
            int k = idx >> 6, l = idx & 63;
            As[k][l] = Ab[(size_t)(kbase + k0 + k) * L_ + l0 + l];
        }
#pragma unroll
        for (int i = 0; i < 4; i++) {
            int idx = i * 256 + tid;
            int n = idx >> 4, k = idx & 15;
            float v = 0.f;
            if (n < XD_) v = Wm[(size_t)n * DI_ + kbase + k0 + k];
            Ws[k][n] = v;
        }
        __syncthreads();
#pragma unroll
        for (int k = 0; k < 16; k++) {
            float4 a4 = *(const float4*)&As[k][tl * 4];
            float4 w4 = *(const float4*)&Ws[k][tn * 4];
            float av[4] = {a4.x, a4.y, a4.z, a4.w};
            float wv[4] = {w4.x, w4.y, w4.z, w4.w};
#pragma unroll
            for (int j = 0; j < 4; j++)
#pragma unroll
                for (int i = 0; i < 4; i++)
                    acc[j][i] += wv[j] * av[i];
        }
        __syncthreads();
    }
#pragma unroll
    for (int j = 0; j < 4; j++) {
        int n = tn * 4 + j;
        if (n >= XD_) continue;
        float4 o = {acc[j][0], acc[j][1], acc[j][2], acc[j][3]};
        *(float4*)&part[(((size_t)b * KSX_ + ks) * XD_ + n) * L_ + l0 + tl * 4] = o;
    }
}

// reduce partials over KSX -> xdbl (B, 56, L)
__global__ __launch_bounds__(256) void xproj_reduce(
    const float* __restrict__ part, float* __restrict__ xdbl)
{
    const int tot = B_ * XD_ * L_ / 4;
    int id = blockIdx.x * 256 + threadIdx.x;
    if (id >= tot) return;
    int per_b = XD_ * L_ / 4;
    int b = id / per_b, rem = id - b * per_b;
    float4 s = {0.f, 0.f, 0.f, 0.f};
#pragma unroll
    for (int ks = 0; ks < KSX_; ks++) {
        float4 v = *(const float4*)&part[((size_t)(b * KSX_ + ks) * XD_) * L_ + (size_t)rem * 4];
        s.x += v.x; s.y += v.y; s.z += v.z; s.w += v.w;
    }
    *(float4*)&xdbl[(size_t)b * XD_ * L_ + (size_t)rem * 4] = s;
}

// ---------------------------------------------------------------------------
// 64x64 fp32 VALU GEMM (delta): C[b][n][l] = act(sum_k A[b][k][l]*W[n][k])
// ---------------------------------------------------------------------------
template<int K, int N, int ACT>
__global__ __launch_bounds__(256) void gemm64(
    const float* __restrict__ A, int aBatch,
    const float* __restrict__ Wm,
    float* __restrict__ C,
    const float* __restrict__ bias)
{
    const int L = L_;
    __shared__ float As[16][64];
    __shared__ float Ws[16][68];
    int tid = threadIdx.x;
    int b  = blockIdx.z;
    int l0 = blockIdx.x * 64;
    int n0 = blockIdx.y * 64;
    const float* Ab = A + (size_t)b * aBatch;
    float acc[4][4];
#pragma unroll
    for (int j = 0; j < 4; j++)
#pragma unroll
        for (int i = 0; i < 4; i++) acc[j][i] = 0.f;
    int tl = tid & 15, tn = tid >> 4;

    for (int k0 = 0; k0 < K; k0 += 16) {
#pragma unroll
        for (int i = 0; i < 4; i++) {
            int idx = i * 256 + tid;
            int k = idx >> 6, l = idx & 63;
            As[k][l] = Ab[(size_t)(k0 + k) * L + l0 + l];
        }
#pragma unroll
        for (int i = 0; i < 4; i++) {
            int idx = i * 256 + tid;
            int n = idx >> 4, k = idx & 15;
            float v = 0.f;
            if (N % 64 == 0 || n0 + n < N)
                v = Wm[(size_t)(n0 + n) * K + k0 + k];
            Ws[k][n] = v;
        }
        __syncthreads();
#pragma unroll
        for (int k = 0; k < 16; k++) {
            float4 a4 = *(const float4*)&As[k][tl * 4];
            float4 w4 = *(const float4*)&Ws[k][tn * 4];
            float av[4] = {a4.x, a4.y, a4.z, a4.w};
            float wv[4] = {w4.x, w4.y, w4.z, w4.w};
#pragma unroll
            for (int j = 0; j < 4; j++)
#pragma unroll
                for (int i = 0; i < 4; i++)
                    acc[j][i] += wv[j] * av[i];
        }
        __syncthreads();
    }
#pragma unroll
    for (int j = 0; j < 4; j++) {
        int n = n0 + tn * 4 + j;
        if (N % 64 != 0 && n >= N) continue;
        float bsn = (ACT == 1) ? bias[n] : 0.f;
        float4 o;
        float* po = &o.x;
#pragma unroll
        for (int i = 0; i < 4; i++) {
            float v = acc[j][i];
            if (ACT == 1) v = softplus_f(v + bsn);
            po[i] = v;
        }
        *(float4*)&C[((size_t)b * N + n) * L + l0 + tl * 4] = o;
    }
}

// ---------------------------------------------------------------------------
// Depthwise 3x3 conv (pad 1) + bias + SiLU. One block per (b, d) plane.
// ---------------------------------------------------------------------------
__global__ __launch_bounds__(256) void conv_silu(
    const float* __restrict__ x, const float* __restrict__ wc,
    const float* __restrict__ bias, float* __restrict__ u)
{
    int d = blockIdx.x, b = blockIdx.y;
    __shared__ float t[66 * 66];
    const float* xp = x + ((size_t)b * DI_ + d) * (size_t)L_;
    int tid = threadIdx.x;
    for (int idx = tid; idx < 66 * 66; idx += 256) {
        int r = idx / 66, c = idx - r * 66;
        int h = r - 1, w2 = c - 1;
        float v = 0.f;
        if (h >= 0 && h < 64 && w2 >= 0 && w2 < 64) v = xp[h * 64 + w2];
        t[idx] = v;
    }
    __syncthreads();
    float w9[9];
#pragma unroll
    for (int i = 0; i < 9; i++) w9[i] = wc[d * 9 + i];
    float bi = bias[d];
    float* up = u + ((size_t)b * DI_ + d) * (size_t)L_;
#pragma unroll
    for (int it = 0; it < 16; it++) {
        int p = it * 256 + tid;
        int h = p >> 6, c = p & 63;
        float s = 0.f;
#pragma unroll
        for (int kh = 0; kh < 3; kh++)
#pragma unroll
            for (int kw = 0; kw < 3; kw++)
                s += t[(h + kh) * 66 + (c + kw)] * w9[kh * 3 + kw];
        s += bi;
        up[p] = silu_f(s);
    }
}

// ---------------------------------------------------------------------------
// Selective scan. One block per (b, d). 256 threads x 16-elem chunks = L=4096.
// ---------------------------------------------------------------------------
__global__ __launch_bounds__(256) void scan_kernel(
    float* __restrict__ dly,          // (B, DI, L): delta in, y out
    const float* __restrict__ u,      // (B, DI, L)
    const float* __restrict__ xdbl,   // (B, 56, L)
    const float* __restrict__ A_log,  // (DI, 4)
    const float* __restrict__ Dp)     // (DI)
{
    const int L = L_;
    int d = blockIdx.x, b = blockIdx.y;
    int tid = threadIdx.x;
    int lane = tid & 63, wv = tid >> 6;
    size_t rowoff = ((size_t)b * DI_ + d) * (size_t)L + tid * 16;
    float dl[16], uu[16];
#pragma unroll
    for (int i = 0; i < 4; i++) {
        *(float4*)&dl[i * 4] = *(const float4*)&dly[rowoff + i * 4];
        *(float4*)&uu[i * 4] = *(const float4*)&u[rowoff + i * 4];
    }
    float An[4];
#pragma unroll
    for (int n = 0; n < 4; n++) An[n] = -expf(A_log[d * 4 + n]);
    float Dd = Dp[d];
    const float* xb = xdbl + (size_t)b * XD_ * L + tid * 16;

    float la[4], ls[4];
#pragma unroll
    for (int n = 0; n < 4; n++) {
        float Bv[16];
#pragma unroll
        for (int i = 0; i < 4; i++)
            *(float4*)&Bv[i * 4] = *(const float4*)&xb[(size_t)(R_ + n) * L + i * 4];
        float aa = 1.f, ss = 0.f;
#pragma unroll
        for (int i = 0; i < 16; i++) {
            float ai = expf(dl[i] * An[n]);
            ss = ai * ss + dl[i] * uu[i] * Bv[i];
            aa *= ai;
        }
        la[n] = aa; ls[n] = ss;
    }
#pragma unroll
    for (int off = 1; off < 64; off <<= 1) {
#pragma unroll
        for (int n = 0; n < 4; n++) {
            float pa = __shfl_up(la[n], off);
            float ps = __shfl_up(ls[n], off);
            if (lane >= off) {
                ls[n] = ls[n] + la[n] * ps;
                la[n] = la[n] * pa;
            }
        }
    }
    float ea[4], es[4];
#pragma unroll
    for (int n = 0; n < 4; n++) {
        ea[n] = __shfl_up(la[n], 1);
        es[n] = __shfl_up(ls[n], 1);
        if (lane == 0) { ea[n] = 1.f; es[n] = 0.f; }
    }
    __shared__ float wsum[4][8];
    if (lane == 63) {
#pragma unroll
        for (int n = 0; n < 4; n++) { wsum[wv][n] = la[n]; wsum[wv][4 + n] = ls[n]; }
    }
    __syncthreads();
    float carry[4];
#pragma unroll
    for (int n = 0; n < 4; n++) {
        float wss = 0.f;
        for (int w2 = 0; w2 < wv; w2++) {
            float a2 = wsum[w2][n], s2 = wsum[w2][4 + n];
            wss = a2 * wss + s2;
        }
        carry[n] = ea[n] * wss + es[n];
    }
    float yv[16];
#pragma unroll
    for (int i = 0; i < 16; i++) yv[i] = Dd * uu[i];
#pragma unroll
    for (int n = 0; n < 4; n++) {
        float Bv[16], Cv[16];
#pragma unroll
        for (int i = 0; i < 4; i++) {
            *(float4*)&Bv[i * 4] = *(const float4*)&xb[(size_t)(R_ + n) * L + i * 4];
            *(float4*)&Cv[i * 4] = *(const float4*)&xb[(size_t)(R_ + 4 + n) * L + i * 4];
        }
        float s = carry[n];
#pragma unroll
        for (int i = 0; i < 16; i++) {
            float ai = expf(dl[i] * An[n]);
            s = ai * s + dl[i] * uu[i] * Bv[i];
            yv[i] += s * Cv[i];
        }
    }
#pragma unroll
    for (int i = 0; i < 4; i++)
        *(float4*)&dly[rowoff + i * 4] = *(const float4*)&yv[i * 4];
}

// ---------------------------------------------------------------------------
// LayerNorm stats over the d (channel) axis of y (B, DI, L).
// ---------------------------------------------------------------------------
__global__ __launch_bounds__(256) void ln_stats(
    const float* __restrict__ y, float* __restrict__ mu, float* __restrict__ rs)
{
    int tid = threadIdx.x;
    int lsub = tid & 31, dg = tid >> 5;
    int l = blockIdx.x * 32 + lsub;
    int b = blockIdx.y;
    const float* yp = y + (size_t)b * DI_ * L_ + l;
    float s = 0.f, s2 = 0.f;
    for (int d = dg; d < DI_; d += 8) {
        float v = yp[(size_t)d * L_];
        s += v; s2 += v * v;
    }
    __shared__ float sh[2][8][32];
    sh[0][dg][lsub] = s; sh[1][dg][lsub] = s2;
    __syncthreads();
    if (dg == 0) {
#pragma unroll
        for (int g2 = 1; g2 < 8; g2++) { s += sh[0][g2][lsub]; s2 += sh[1][g2][lsub]; }
        const float inv = 1.f / DI_;
        float m = s * inv;
        float var = s2 * inv - m * m;
        mu[b * L_ + l] = m;
        rs[b * L_ + l] = rsqrtf(var + 1e-5f);
    }
}

extern "C" void kernel_launch(void* const* d_in, const int* in_sizes, int n_in,
                              void* d_out, int out_size, void* d_ws, size_t ws_size,
                              hipStream_t stream)
{
    const float* hidden = (const float*)d_in[0];   // (B, DM, H, W)
    const float* in_w   = (const float*)d_in[1];   // (DI, DM)
    const float* conv_w = (const float*)d_in[2];   // (DI, 1, 3, 3)
    const float* conv_b = (const float*)d_in[3];   // (DI)
    const float* xp_w   = (const float*)d_in[4];   // (56, DI)
    const float* dt_w   = (const float*)d_in[5];   // (1, DI, 48)
    const float* dt_b   = (const float*)d_in[6];   // (1, DI)
    const float* A_log  = (const float*)d_in[7];   // (1, DI, 4)
    const float* Dp     = (const float*)d_in[8];   // (1, DI)
    const float* ln_g   = (const float*)d_in[9];   // (DI)
    const float* ln_b   = (const float*)d_in[10];  // (DI)
    const float* out_w  = (const float*)d_in[11];  // (DM, DI)
    float* out = (float*)d_out;                    // (B, DM, L)

    const size_t BIG = (size_t)B_ * DI_ * L_;
    float* big1 = (float*)d_ws;                    // x -> delta -> y (in place)
    float* big2 = big1 + BIG;                      // u
    float* xdbl = big2 + BIG;                      // (B, 56, L)
    float* mu   = xdbl + (size_t)B_ * XD_ * L_;
    float* rs   = mu + (size_t)B_ * L_;
    unsigned short* pack = (unsigned short*)(rs + (size_t)B_ * L_);

    const size_t NK = (size_t)DI_ * DM_;                       // W elems (both GEMMs)
    const size_t XPK = (size_t)B_ * 32 * (DM_ / 32) * 5120;    // packed X ushorts
    const size_t YPK = (size_t)B_ * 32 * (DI_ / 32) * 5120;    // packed Y ushorts
    unsigned short* wh = pack;
    unsigned short* wlo = pack + NK;
    unsigned short* xh = pack + 2 * NK;
    // x_proj partials alias the (dead after in_proj) packed-X region: 22MB <= 31.5MB
    float* xpart = (float*)(pack + 2 * NK);

    // ---- phase 1: in_proj on MFMA ----
    split_w<<<(int)(NK / 4 / 256), 256, 0, stream>>>(in_w, wh, wlo, (int)(NK / 4));
    pack_x<DM_, false><<<dim3(DM_ / 32, 32, B_), 256, 0, stream>>>(
        hidden, xh, xh + XPK, nullptr, nullptr, nullptr, nullptr);
    gemm_mfma<DM_, 4><<<dim3(32, DI_ / 128, B_), 256, 0, stream>>>(
        wh, wlo, xh, xh + XPK, big1, DI_);

    // ---- middle: conv + x_proj(split-K) + delta + scan + ln stats ----
    conv_silu<<<dim3(DI_, B_), 256, 0, stream>>>(big1, conv_w, conv_b, big2);
    xproj_sk<<<dim3(L_ / 64, KSX_, B_), 256, 0, stream>>>(big2, xp_w, xpart);
    xproj_reduce<<<(B_ * XD_ * L_ / 4 + 255) / 256, 256, 0, stream>>>(xpart, xdbl);
    gemm64<R_, DI_, 1><<<dim3(L_ / 64, DI_ / 64, B_), 256, 0, stream>>>(
        xdbl, XD_ * L_, dt_w, big1, dt_b);
    scan_kernel<<<dim3(DI_, B_), 256, 0, stream>>>(big1, big2, xdbl, A_log, Dp);
    ln_stats<<<dim3(L_ / 32, B_), 256, 0, stream>>>(big1, mu, rs);

    // ---- phase 2: out_proj on MFMA (LN fused into pack) ----
    split_w<<<(int)(NK / 4 / 256), 256, 0, stream>>>(out_w, wh, wlo, (int)(NK / 4));
    unsigned short* yh = pack + 2 * NK;
    pack_x<DI_, true><<<dim3(DI_ / 32, 32, B_), 256, 0, stream>>>(
        big1, yh, yh + YPK, mu, rs, ln_g, ln_b);
    gemm_mfma<DI_, 2><<<dim3(32, DM_ / 64, B_), 256, 0, stream>>>(
        wh, wlo, yh, yh + YPK, out, DM_);
}

// Round 8
// 549.018 us; speedup vs baseline: 2.0410x; 1.0116x over previous
//
#include <hip/hip_runtime.h>
#include <math.h>

#define B_   2
#define DM_  768
#define L_   4096
#define DI_  1536
#define NS_  4
#define R_   48
#define XD_  56   // R + 2*NS

#define KSX_  12    // x_proj K splits
#define KCHX_ 128   // DI_ / KSX_

typedef __attribute__((ext_vector_type(8))) short s16x8;
typedef __attribute__((ext_vector_type(4))) float f32x4;
typedef __attribute__((ext_vector_type(8))) unsigned short us8;
typedef __attribute__((ext_vector_type(4))) unsigned short us4;

__device__ __forceinline__ float softplus_f(float x) {
    return fmaxf(x, 0.f) + log1pf(expf(-fabsf(x)));
}
__device__ __forceinline__ float silu_f(float x) {
    return x / (1.f + expf(-x));
}

// round-to-nearest bf16 (inputs finite)
__device__ __forceinline__ unsigned short bf16_rn(float v) {
    unsigned u = __float_as_uint(v);
    u += 0x7FFFu + ((u >> 16) & 1u);
    return (unsigned short)(u >> 16);
}
// v ~= hi + lo with ~16-bit effective mantissa
__device__ __forceinline__ void split2(float v, unsigned short& h, unsigned short& l) {
    h = bf16_rn(v);
    float fh = __uint_as_float(((unsigned)h) << 16);
    l = bf16_rn(v - fh);
}

__device__ __forceinline__ void cp16(const void* g, void* l) {
    __builtin_amdgcn_global_load_lds(
        (const __attribute__((address_space(1))) unsigned int*)g,
        (__attribute__((address_space(3))) unsigned int*)l, 16, 0, 0);
}

// ---------------------------------------------------------------------------
// Split a weight matrix (N,K) fp32 row-major -> flat bf16 hi/lo (same layout).
// ---------------------------------------------------------------------------
__global__ __launch_bounds__(256) void split_w(const float* __restrict__ W,
    unsigned short* __restrict__ Wh, unsigned short* __restrict__ Wl, int n4)
{
    int id = blockIdx.x * 256 + threadIdx.x;
    if (id >= n4) return;
    float4 v = *(const float4*)(W + (size_t)id * 4);
    us4 h, l;
    unsigned short hh, ll;
    split2(v.x, hh, ll); h[0] = hh; l[0] = ll;
    split2(v.y, hh, ll); h[1] = hh; l[1] = ll;
    split2(v.z, hh, ll); h[2] = hh; l[2] = ll;
    split2(v.w, hh, ll); h[3] = hh; l[3] = ll;
    *(us4*)(Wh + (size_t)id * 4) = h;
    *(us4*)(Wl + (size_t)id * 4) = l;
}

// ---------------------------------------------------------------------------
// Pack activations X (B,K,L) fp32 l-major into k-contiguous padded bf16 tiles:
// per (b, l-tile of 128, k-tile of 32): 128 rows x (32 bf16 + 8 pad) = 80B/row.
// Tile base (ushorts): ((b*32 + lt)*KT + kt) * 5120; elem: + l*40 + k.
// ---------------------------------------------------------------------------
template<int K, bool LN>
__global__ __launch_bounds__(256) void pack_x(
    const float* __restrict__ X,
    unsigned short* __restrict__ Xh, unsigned short* __restrict__ Xl,
    const float* __restrict__ mu, const float* __restrict__ rs,
    const float* __restrict__ g, const float* __restrict__ be)
{
    const int KT = K / 32;
    int kt = blockIdx.x, lt = blockIdx.y, b = blockIdx.z;
    __shared__ float t[32][133];
    int tid = threadIdx.x;
    const float* Xp = X + ((size_t)b * K + kt * 32) * L_ + lt * 128;
#pragma unroll
    for (int i = 0; i < 4; ++i) {
        int id = i * 256 + tid;
        int k = id >> 5, f4 = id & 31;
        float4 v = *(const float4*)(Xp + (size_t)k * L_ + f4 * 4);
        t[k][f4 * 4]     = v.x;
        t[k][f4 * 4 + 1] = v.y;
        t[k][f4 * 4 + 2] = v.z;
        t[k][f4 * 4 + 3] = v.w;
    }
    __syncthreads();
    size_t tb = ((size_t)(b * 32 + lt) * KT + kt) * 5120;
    unsigned short* ph = Xh + tb;
    unsigned short* pl = Xl + tb;
#pragma unroll
    for (int i = 0; i < 2; ++i) {
        int id = i * 256 + tid;
        int l = id >> 2, kbv = id & 3;
        float m = 0.f, r = 1.f;
        if (LN) { m = mu[b * L_ + lt * 128 + l]; r = rs[b * L_ + lt * 128 + l]; }
        us8 hv, lv;
#pragma unroll
        for (int j = 0; j < 8; ++j) {
            int k = kbv * 8 + j;
            float v = t[k][l];
            if (LN) v = (v - m) * r * g[kt * 32 + k] + be[kt * 32 + k];
            unsigned short hh, ll;
            split2(v, hh, ll);
            hv[j] = hh; lv[j] = ll;
        }
        *(us8*)(ph + l * 40 + kbv * 8) = hv;
        *(us8*)(pl + l * 40 + kbv * 8) = lv;
    }
}

// ---------------------------------------------------------------------------
// MFMA GEMM: C[b][n][l] = sum_k W[n][k] * X[b][k][l], fp32 out.
// bf16 hi/lo 3-term emulation: Wh*Xh + Wh*Xl + Wl*Xh (fp32 accumulate).
// 2-phase double-buffered pipeline: stage tile kt+1 BEFORE computing tile kt;
// one raw s_barrier + vmcnt(0) per K-step (next-tile loads fly over the MFMAs).
// XCD-chunked bijective swizzle, nt-fastest decode.
// ---------------------------------------------------------------------------
template<int K, int MBF>
__global__ __launch_bounds__(256) void gemm_mfma(
    const unsigned short* __restrict__ Wh, const unsigned short* __restrict__ Wl,
    const unsigned short* __restrict__ Xh, const unsigned short* __restrict__ Xl,
    float* __restrict__ C, int N)
{
    const int KT = K / 32;
    const int BN = MBF * 32;
    __shared__ unsigned short lds[2][10240];
    int tid = threadIdx.x;
    // --- XCD chunked swizzle (nwg = 32*NT*B, divisible by 8) ---
    int NT = gridDim.y;
    int nwg = 32 * NT * (int)gridDim.z;
    int bid = blockIdx.x + 32 * (blockIdx.y + NT * blockIdx.z);
    int cpx = nwg >> 3;
    int swz = (bid & 7) * cpx + (bid >> 3);
    int nt = swz % NT; int t2 = swz / NT;
    int lt = t2 & 31;  int b  = t2 >> 5;

    int lane = tid & 63, w = tid >> 6;
    int wn = (w >> 1) * (MBF * 16), wl = (w & 1) * 64;
    int row = lane & 15, kb = lane >> 4;

    const unsigned short* xh_t = Xh + ((size_t)(b * 32 + lt) * KT) * 5120;
    const unsigned short* xl_t = Xl + ((size_t)(b * 32 + lt) * KT) * 5120;
    const unsigned short* wh_p = Wh + (size_t)(nt * BN + wn + row) * K + kb * 8;
    const unsigned short* wl_p = Wl + (size_t)(nt * BN + wn + row) * K + kb * 8;

    f32x4 acc[MBF][4];
#pragma unroll
    for (int m = 0; m < MBF; m++)
#pragma unroll
        for (int l2 = 0; l2 < 4; l2++) acc[m][l2] = (f32x4){0.f, 0.f, 0.f, 0.f};

    // stage one 2x5120-ushort tile (hi+lo) into LDS buffer bb
    auto stage = [&](int bb, int kt) {
        const unsigned short* sh = xh_t + (size_t)kt * 5120;
        const unsigned short* sl = xl_t + (size_t)kt * 5120;
#pragma unroll
        for (int i = 0; i < 3; ++i) {
            int slot = i * 256 + tid;               // 640 x 16B per tile
            if (slot < 640) {
                int lbase = (i * 256 + (tid & 192)) * 8;   // wave-uniform LDS base
                cp16(sh + slot * 8, &lds[bb][lbase]);
                cp16(sl + slot * 8, &lds[bb][5120 + lbase]);
            }
        }
    };

    // prologue: fill buffer 0
    stage(0, 0);
    asm volatile("s_waitcnt vmcnt(0)" ::: "memory");
    __builtin_amdgcn_s_barrier();

    int cur = 0;
    for (int kt = 0; kt < KT; ++kt) {
        // issue next tile's loads early — they stay in flight across the MFMAs
        if (kt + 1 < KT) stage(cur ^ 1, kt + 1);
        // W fragments for this K-step (per-lane global loads, L2-resident)
        s16x8 ah[MBF], al[MBF];
#pragma unroll
        for (int m = 0; m < MBF; m++) {
            ah[m] = *(const s16x8*)(wh_p + (size_t)m * 16 * K + kt * 32);
            al[m] = *(const s16x8*)(wl_p + (size_t)m * 16 * K + kt * 32);
        }
        // current tile from LDS
        s16x8 bh[4], bl[4];
#pragma unroll
        for (int l2 = 0; l2 < 4; l2++) {
            int off = (wl + l2 * 16 + row) * 40 + kb * 8;
            bh[l2] = *(const s16x8*)&lds[cur][off];
            bl[l2] = *(const s16x8*)&lds[cur][5120 + off];
        }
#pragma unroll
        for (int m = 0; m < MBF; m++)
#pragma unroll
            for (int l2 = 0; l2 < 4; l2++) {
                acc[m][l2] = __builtin_amdgcn_mfma_f32_16x16x32_bf16(ah[m], bh[l2], acc[m][l2], 0, 0, 0);
                acc[m][l2] = __builtin_amdgcn_mfma_f32_16x16x32_bf16(ah[m], bl[l2], acc[m][l2], 0, 0, 0);
                acc[m][l2] = __builtin_amdgcn_mfma_f32_16x16x32_bf16(al[m], bh[l2], acc[m][l2], 0, 0, 0);
            }
        // next tile staged + all waves done reading cur -> flip
        asm volatile("s_waitcnt vmcnt(0)" ::: "memory");
        __builtin_amdgcn_s_barrier();
        cur ^= 1;
    }
    float* Cp = C + ((size_t)b * N + nt * BN) * L_ + (size_t)lt * 128;
#pragma unroll
    for (int m = 0; m < MBF; m++)
#pragma unroll
        for (int l2 = 0; l2 < 4; l2++) {
            int lcol = wl + l2 * 16 + row;
#pragma unroll
            for (int j = 0; j < 4; j++) {
                int nrow = wn + m * 16 + kb * 4 + j;
                Cp[(size_t)nrow * L_ + lcol] = acc[m][l2][j];
            }
        }
}

// ---------------------------------------------------------------------------
// x_proj split-K stage 1: part[b][ks][n][l] = sum_{k in chunk} u[b][k][l]*W[n][k]
// 64l x 56n tile, K-chunk 128. Grid (L/64, KSX, B) = 1536 blocks.
// ---------------------------------------------------------------------------
__global__ __launch_bounds__(256) void xproj_sk(
    const float* __restrict__ u, const float* __restrict__ Wm,
    float* __restrict__ part)
{
    __shared__ float As[16][64];
    __shared__ float Ws[16][68];
    int tid = threadIdx.x;
    int l0 = blockIdx.x * 64;
    int ks = blockIdx.y;
    int b  = blockIdx.z;
    int kbase = ks * KCHX_;
    const float* Ab = u + (size_t)b * DI_ * L_;
    float acc[4][4];
#pragma unroll
    for (int j = 0; j < 4; j++)
#pragma unroll
        for (int i = 0; i < 4; i++) acc[j][i] = 0.f;
    int tl = tid & 15, tn = tid >> 4;

    for (int k0 = 0; k0 < KCHX_; k0 += 16) {
#pragma unroll
        for (int i = 0; i < 4; i++) {
            int idx = i * 256 + tid;
            int k = idx >> 6, l = idx & 63;
            As[k][l] = Ab[(size_t)(kbase + k0 + k) * L_ + l0 + l];
        }
#pragma unroll
        for (int i = 0; i < 4; i++) {
            int idx = i * 256 + tid;
            int n = idx >> 4, k = idx & 15;
            float v = 0.f;
            if (n < XD_) v = Wm[(size_t)n * DI_ + kbase + k0 + k];
            Ws[k][n] = v;
        }
        __syncthreads();
#pragma unroll
        for (int k = 0; k < 16; k++) {
            float4 a4 = *(const float4*)&As[k][tl * 4];
            float4 w4 = *(const float4*)&Ws[k][tn * 4];
            float av[4] = {a4.x, a4.y, a4.z, a4.w};
            float wv[4] = {w4.x, w4.y, w4.z, w4.w};
#pragma unroll
            for (int j = 0; j < 4; j++)
#pragma unroll
                for (int i = 0; i < 4; i++)
                    acc[j][i] += wv[j] * av[i];
        }
        __syncthreads();
    }
#pragma unroll
    for (int j = 0; j < 4; j++) {
        int n = tn * 4 + j;
        if (n >= XD_) continue;
        float4 o = {acc[j][0], acc[j][1], acc[j][2], acc[j][3]};
        *(float4*)&part[(((size_t)b * KSX_ + ks) * XD_ + n) * L_ + l0 + tl * 4] = o;
    }
}

// reduce partials over KSX -> xdbl (B, 56, L)
__global__ __launch_bounds__(256) void xproj_reduce(
    const float* __restrict__ part, float* __restrict__ xdbl)
{
    const int tot = B_ * XD_ * L_ / 4;
    int id = blockIdx.x * 256 + threadIdx.x;
    if (id >= tot) return;
    int per_b = XD_ * L_ / 4;
    int b = id / per_b, rem = id - b * per_b;
    float4 s = {0.f, 0.f, 0.f, 0.f};
#pragma unroll
    for (int ks = 0; ks < KSX_; ks++) {
        float4 v = *(const float4*)&part[((size_t)(b * KSX_ + ks) * XD_) * L_ + (size_t)rem * 4];
        s.x += v.x; s.y += v.y; s.z += v.z; s.w += v.w;
    }
    *(float4*)&xdbl[(size_t)b * XD_ * L_ + (size_t)rem * 4] = s;
}

// ---------------------------------------------------------------------------
// 64x64 fp32 VALU GEMM (delta): C[b][n][l] = act(sum_k A[b][k][l]*W[n][k])
// ---------------------------------------------------------------------------
template<int K, int N, int ACT>
__global__ __launch_bounds__(256) void gemm64(
    const float* __restrict__ A, int aBatch,
    const float* __restrict__ Wm,
    float* __restrict__ C,
    const float* __restrict__ bias)
{
    const int L = L_;
    __shared__ float As[16][64];
    __shared__ float Ws[16][68];
    int tid = threadIdx.x;
    int b  = blockIdx.z;
    int l0 = blockIdx.x * 64;
    int n0 = blockIdx.y * 64;
    const float* Ab = A + (size_t)b * aBatch;
    float acc[4][4];
#pragma unroll
    for (int j = 0; j < 4; j++)
#pragma unroll
        for (int i = 0; i < 4; i++) acc[j][i] = 0.f;
    int tl = tid & 15, tn = tid >> 4;

    for (int k0 = 0; k0 < K; k0 += 16) {
#pragma unroll
        for (int i = 0; i < 4; i++) {
            int idx = i * 256 + tid;
            int k = idx >> 6, l = idx & 63;
            As[k][l] = Ab[(size_t)(k0 + k) * L + l0 + l];
        }
#pragma unroll
        for (int i = 0; i < 4; i++) {
            int idx = i * 256 + tid;
            int n = idx >> 4, k = idx & 15;
            float v = 0.f;
            if (N % 64 == 0 || n0 + n < N)
                v = Wm[(size_t)(n0 + n) * K + k0 + k];
            Ws[k][n] = v;
        }
        __syncthreads();
#pragma unroll
        for (int k = 0; k < 16; k++) {
            float4 a4 = *(const float4*)&As[k][tl * 4];
            float4 w4 = *(const float4*)&Ws[k][tn * 4];
            float av[4] = {a4.x, a4.y, a4.z, a4.w};
            float wv[4] = {w4.x, w4.y, w4.z, w4.w};
#pragma unroll
            for (int j = 0; j < 4; j++)
#pragma unroll
                for (int i = 0; i < 4; i++)
                    acc[j][i] += wv[j] * av[i];
        }
        __syncthreads();
    }
#pragma unroll
    for (int j = 0; j < 4; j++) {
        int n = n0 + tn * 4 + j;
        if (N % 64 != 0 && n >= N) continue;
        float bsn = (ACT == 1) ? bias[n] : 0.f;
        float4 o;
        float* po = &o.x;
#pragma unroll
        for (int i = 0; i < 4; i++) {
            float v = acc[j][i];
            if (ACT == 1) v = softplus_f(v + bsn);
            po[i] = v;
        }
        *(float4*)&C[((size_t)b * N + n) * L + l0 + tl * 4] = o;
    }
}

// ---------------------------------------------------------------------------
// Depthwise 3x3 conv (pad 1) + bias + SiLU. One block per (b, d) plane.
// ---------------------------------------------------------------------------
__global__ __launch_bounds__(256) void conv_silu(
    const float* __restrict__ x, const float* __restrict__ wc,
    const float* __restrict__ bias, float* __restrict__ u)
{
    int d = blockIdx.x, b = blockIdx.y;
    __shared__ float t[66 * 66];
    const float* xp = x + ((size_t)b * DI_ + d) * (size_t)L_;
    int tid = threadIdx.x;
    for (int idx = tid; idx < 66 * 66; idx += 256) {
        int r = idx / 66, c = idx - r * 66;
        int h = r - 1, w2 = c - 1;
        float v = 0.f;
        if (h >= 0 && h < 64 && w2 >= 0 && w2 < 64) v = xp[h * 64 + w2];
        t[idx] = v;
    }
    __syncthreads();
    float w9[9];
#pragma unroll
    for (int i = 0; i < 9; i++) w9[i] = wc[d * 9 + i];
    float bi = bias[d];
    float* up = u + ((size_t)b * DI_ + d) * (size_t)L_;
#pragma unroll
    for (int it = 0; it < 16; it++) {
        int p = it * 256 + tid;
        int h = p >> 6, c = p & 63;
        float s = 0.f;
#pragma unroll
        for (int kh = 0; kh < 3; kh++)
#pragma unroll
            for (int kw = 0; kw < 3; kw++)
                s += t[(h + kh) * 66 + (c + kw)] * w9[kh * 3 + kw];
        s += bi;
        up[p] = silu_f(s);
    }
}

// ---------------------------------------------------------------------------
// Selective scan. One block per (b, d). 256 threads x 16-elem chunks = L=4096.
// ---------------------------------------------------------------------------
__global__ __launch_bounds__(256) void scan_kernel(
    float* __restrict__ dly,          // (B, DI, L): delta in, y out
    const float* __restrict__ u,      // (B, DI, L)
    const float* __restrict__ xdbl,   // (B, 56, L)
    const float* __restrict__ A_log,  // (DI, 4)
    const float* __restrict__ Dp)     // (DI)
{
    const int L = L_;
    int d = blockIdx.x, b = blockIdx.y;
    int tid = threadIdx.x;
    int lane = tid & 63, wv = tid >> 6;
    size_t rowoff = ((size_t)b * DI_ + d) * (size_t)L + tid * 16;
    float dl[16], uu[16];
#pragma unroll
    for (int i = 0; i < 4; i++) {
        *(float4*)&dl[i * 4] = *(const float4*)&dly[rowoff + i * 4];
        *(float4*)&uu[i * 4] = *(const float4*)&u[rowoff + i * 4];
    }
    float An[4];
#pragma unroll
    for (int n = 0; n < 4; n++) An[n] = -expf(A_log[d * 4 + n]);
    float Dd = Dp[d];
    const float* xb = xdbl + (size_t)b * XD_ * L + tid * 16;

    float la[4], ls[4];
#pragma unroll
    for (int n = 0; n < 4; n++) {
        float Bv[16];
#pragma unroll
        for (int i = 0; i < 4; i++)
            *(float4*)&Bv[i * 4] = *(const float4*)&xb[(size_t)(R_ + n) * L + i * 4];
        float aa = 1.f, ss = 0.f;
#pragma unroll
        for (int i = 0; i < 16; i++) {
            float ai = expf(dl[i] * An[n]);
            ss = ai * ss + dl[i] * uu[i] * Bv[i];
            aa *= ai;
        }
        la[n] = aa; ls[n] = ss;
    }
#pragma unroll
    for (int off = 1; off < 64; off <<= 1) {
#pragma unroll
        for (int n = 0; n < 4; n++) {
            float pa = __shfl_up(la[n], off);
            float ps = __shfl_up(ls[n], off);
            if (lane >= off) {
                ls[n] = ls[n] + la[n] * ps;
                la[n] = la[n] * pa;
            }
        }
    }
    float ea[4], es[4];
#pragma unroll
    for (int n = 0; n < 4; n++) {
        ea[n] = __shfl_up(la[n], 1);
        es[n] = __shfl_up(ls[n], 1);
        if (lane == 0) { ea[n] = 1.f; es[n] = 0.f; }
    }
    __shared__ float wsum[4][8];
    if (lane == 63) {
#pragma unroll
        for (int n = 0; n < 4; n++) { wsum[wv][n] = la[n]; wsum[wv][4 + n] = ls[n]; }
    }
    __syncthreads();
    float carry[4];
#pragma unroll
    for (int n = 0; n < 4; n++) {
        float wss = 0.f;
        for (int w2 = 0; w2 < wv; w2++) {
            float a2 = wsum[w2][n], s2 = wsum[w2][4 + n];
            wss = a2 * wss + s2;
        }
        carry[n] = ea[n] * wss + es[n];
    }
    float yv[16];
#pragma unroll
    for (int i = 0; i < 16; i++) yv[i] = Dd * uu[i];
#pragma unroll
    for (int n = 0; n < 4; n++) {
        float Bv[16], Cv[16];
#pragma unroll
        for (int i = 0; i < 4; i++) {
            *(float4*)&Bv[i * 4] = *(const float4*)&xb[(size_t)(R_ + n) * L + i * 4];
            *(float4*)&Cv[i * 4] = *(const float4*)&xb[(size_t)(R_ + 4 + n) * L + i * 4];
        }
        float s = carry[n];
#pragma unroll
        for (int i = 0; i < 16; i++) {
            float ai = expf(dl[i] * An[n]);
            s = ai * s + dl[i] * uu[i] * Bv[i];
            yv[i] += s * Cv[i];
        }
    }
#pragma unroll
    for (int i = 0; i < 4; i++)
        *(float4*)&dly[rowoff + i * 4] = *(const float4*)&yv[i * 4];
}

// ---------------------------------------------------------------------------
// LayerNorm stats over the d (channel) axis of y (B, DI, L).
// ---------------------------------------------------------------------------
__global__ __launch_bounds__(256) void ln_stats(
    const float* __restrict__ y, float* __restrict__ mu, float* __restrict__ rs)
{
    int tid = threadIdx.x;
    int lsub = tid & 31, dg = tid >> 5;
    int l = blockIdx.x * 32 + lsub;
    int b = blockIdx.y;
    const float* yp = y + (size_t)b * DI_ * L_ + l;
    float s = 0.f, s2 = 0.f;
    for (int d = dg; d < DI_; d += 8) {
        float v = yp[(size_t)d * L_];
        s += v; s2 += v * v;
    }
    __shared__ float sh[2][8][32];
    sh[0][dg][lsub] = s; sh[1][dg][lsub] = s2;
    __syncthreads();
    if (dg == 0) {
#pragma unroll
        for (int g2 = 1; g2 < 8; g2++) { s += sh[0][g2][lsub]; s2 += sh[1][g2][lsub]; }
        const float inv = 1.f / DI_;
        float m = s * inv;
        float var = s2 * inv - m * m;
        mu[b * L_ + l] = m;
        rs[b * L_ + l] = rsqrtf(var + 1e-5f);
    }
}

extern "C" void kernel_launch(void* const* d_in, const int* in_sizes, int n_in,
                              void* d_out, int out_size, void* d_ws, size_t ws_size,
                              hipStream_t stream)
{
    const float* hidden = (const float*)d_in[0];   // (B, DM, H, W)
    const float* in_w   = (const float*)d_in[1];   // (DI, DM)
    const float* conv_w = (const float*)d_in[2];   // (DI, 1, 3, 3)
    const float* conv_b = (const float*)d_in[3];   // (DI)
    const float* xp_w   = (const float*)d_in[4];   // (56, DI)
    const float* dt_w   = (const float*)d_in[5];   // (1, DI, 48)
    const float* dt_b   = (const float*)d_in[6];   // (1, DI)
    const float* A_log  = (const float*)d_in[7];   // (1, DI, 4)
    const float* Dp     = (const float*)d_in[8];   // (1, DI)
    const float* ln_g   = (const float*)d_in[9];   // (DI)
    const float* ln_b   = (const float*)d_in[10];  // (DI)
    const float* out_w  = (const float*)d_in[11];  // (DM, DI)
    float* out = (float*)d_out;                    // (B, DM, L)

    const size_t BIG = (size_t)B_ * DI_ * L_;
    float* big1 = (float*)d_ws;                    // x -> delta -> y (in place)
    float* big2 = big1 + BIG;                      // u
    float* xdbl = big2 + BIG;                      // (B, 56, L)
    float* mu   = xdbl + (size_t)B_ * XD_ * L_;
    float* rs   = mu + (size_t)B_ * L_;
    unsigned short* pack = (unsigned short*)(rs + (size_t)B_ * L_);

    const size_t NK = (size_t)DI_ * DM_;                       // W elems (both GEMMs)
    const size_t XPK = (size_t)B_ * 32 * (DM_ / 32) * 5120;    // packed X ushorts
    const size_t YPK = (size_t)B_ * 32 * (DI_ / 32) * 5120;    // packed Y ushorts
    unsigned short* wh = pack;
    unsigned short* wlo = pack + NK;
    unsigned short* xh = pack + 2 * NK;
    // x_proj partials alias the (dead after in_proj) packed-X region: 22MB <= 31.5MB
    float* xpart = (float*)(pack + 2 * NK);

    // ---- phase 1: in_proj on MFMA ----
    split_w<<<(int)(NK / 4 / 256), 256, 0, stream>>>(in_w, wh, wlo, (int)(NK / 4));
    pack_x<DM_, false><<<dim3(DM_ / 32, 32, B_), 256, 0, stream>>>(
        hidden, xh, xh + XPK, nullptr, nullptr, nullptr, nullptr);
    gemm_mfma<DM_, 4><<<dim3(32, DI_ / 128, B_), 256, 0, stream>>>(
        wh, wlo, xh, xh + XPK, big1, DI_);

    // ---- middle: conv + x_proj(split-K) + delta + scan + ln stats ----
    conv_silu<<<dim3(DI_, B_), 256, 0, stream>>>(big1, conv_w, conv_b, big2);
    xproj_sk<<<dim3(L_ / 64, KSX_, B_), 256, 0, stream>>>(big2, xp_w, xpart);
    xproj_reduce<<<(B_ * XD_ * L_ / 4 + 255) / 256, 256, 0, stream>>>(xpart, xdbl);
    gemm64<R_, DI_, 1><<<dim3(L_ / 64, DI_ / 64, B_), 256, 0, stream>>>(
        xdbl, XD_ * L_, dt_w, big1, dt_b);
    scan_kernel<<<dim3(DI_, B_), 256, 0, stream>>>(big1, big2, xdbl, A_log, Dp);
    ln_stats<<<dim3(L_ / 32, B_), 256, 0, stream>>>(big1, mu, rs);

    // ---- phase 2: out_proj on MFMA (LN fused into pack) ----
    split_w<<<(int)(NK / 4 / 256), 256, 0, stream>>>(out_w, wh, wlo, (int)(NK / 4));
    unsigned short* yh = pack + 2 * NK;
    pack_x<DI_, true><<<dim3(DI_ / 32, 32, B_), 256, 0, stream>>>(
        big1, yh, yh + YPK, mu, rs, ln_g, ln_b);
    gemm_mfma<DI_, 2><<<dim3(32, DM_ / 64, B_), 256, 0, stream>>>(
        wh, wlo, yh, yh + YPK, out, DM_);
}